// Round 1
// baseline (646.594 us; speedup 1.0000x reference)
//
#include <hip/hip_runtime.h>

// ---------- types ----------
typedef __bf16 bf16_t;
typedef __bf16 bf16x4_t __attribute__((ext_vector_type(4)));
typedef __bf16 bf16x8_t __attribute__((ext_vector_type(8)));
typedef float  f32x4_t  __attribute__((ext_vector_type(4)));
typedef unsigned int u32x4_t __attribute__((ext_vector_type(4)));
typedef unsigned short u16;

#define MFMA_BF16(a, b, c) __builtin_amdgcn_mfma_f32_16x16x32_bf16((a), (b), (c), 0, 0, 0)

static __device__ __forceinline__ f32x4_t zero4() {
  f32x4_t z; z[0] = 0.f; z[1] = 0.f; z[2] = 0.f; z[3] = 0.f; return z;
}
static __device__ __forceinline__ bf16x8_t load8(const void* p) {
  return __builtin_bit_cast(bf16x8_t, *reinterpret_cast<const u32x4_t*>(p));
}

// ---------- problem constants ----------
constexpr int BB = 4, SS = 2048, DD = 1024, HH = 16, HDD = 64;
constexpr int MR = BB * SS;          // 8192 rows
constexpr int NQKV = 3 * DD;         // 3072

// ---------- x f32 -> bf16 ----------
__global__ __launch_bounds__(256, 2) void k_convert_x(const float* __restrict__ x,
                                                      bf16_t* __restrict__ xb) {
  int i = blockIdx.x * 256 + threadIdx.x;            // 4 elems each
  f32x4_t v = reinterpret_cast<const f32x4_t*>(x)[i];
  bf16x4_t o;
  o[0] = (bf16_t)v[0]; o[1] = (bf16_t)v[1]; o[2] = (bf16_t)v[2]; o[3] = (bf16_t)v[3];
  reinterpret_cast<bf16x4_t*>(xb)[i] = o;
}

// ---------- W [KD][ND] f32  ->  WT [ND][KD] bf16 ----------
template <int KD, int ND>
__global__ __launch_bounds__(256, 2) void k_transpose(const float* __restrict__ W,
                                                      bf16_t* __restrict__ WT) {
  __shared__ float tile[64][65];
  const int nt = ND / 64;
  int bx = blockIdx.x % nt;      // n tile
  int by = blockIdx.x / nt;      // k tile
  int k0 = by * 64, n0 = bx * 64;
  int t = threadIdx.x, cc = t & 63;
#pragma unroll
  for (int i = 0; i < 16; ++i) {
    int rr = (t >> 6) + i * 4;
    tile[rr][cc] = W[(k0 + rr) * ND + n0 + cc];
  }
  __syncthreads();
#pragma unroll
  for (int i = 0; i < 16; ++i) {
    int rr = (t >> 6) + i * 4;                       // n-row
    WT[(n0 + rr) * (long)KD + k0 + cc] = (bf16_t)tile[cc][rr];
  }
}

// ---------- shared 128x128xK GEMM core (A[M][1024] bf16, BT[N][1024] bf16) ----------
__device__ __forceinline__ void gemm_core_128(const bf16_t* __restrict__ A,
                                              const bf16_t* __restrict__ BT,
                                              int m0, int n0,
                                              u16* As, u16* Bs, f32x4_t acc[4][4]) {
  const int tid = threadIdx.x;
  const int w = tid >> 6, l = tid & 63;
  const int g = l >> 4, li = l & 15;
  const int wm = w >> 1, wn = w & 1;
#pragma unroll
  for (int i = 0; i < 4; ++i)
#pragma unroll
    for (int j = 0; j < 4; ++j) acc[i][j] = zero4();

  for (int kt = 0; kt < 16; ++kt) {
    const int k0 = kt * 64;
#pragma unroll
    for (int i = 0; i < 4; ++i) {
      int flat = i * 256 + tid;
      int row = flat >> 3, seg = flat & 7;
      u32x4_t va = *reinterpret_cast<const u32x4_t*>(A + (long)(m0 + row) * 1024 + k0 + seg * 8);
      u32x4_t vb = *reinterpret_cast<const u32x4_t*>(BT + (long)(n0 + row) * 1024 + k0 + seg * 8);
      *reinterpret_cast<u32x4_t*>(&As[row * 80 + seg * 8]) = va;
      *reinterpret_cast<u32x4_t*>(&Bs[row * 80 + seg * 8]) = vb;
    }
    __syncthreads();
#pragma unroll
    for (int kk = 0; kk < 2; ++kk) {
      bf16x8_t af[4], bfr[4];
#pragma unroll
      for (int f = 0; f < 4; ++f) {
        af[f]  = load8(&As[(wm * 64 + f * 16 + li) * 80 + kk * 32 + g * 8]);
        bfr[f] = load8(&Bs[(wn * 64 + f * 16 + li) * 80 + kk * 32 + g * 8]);
      }
#pragma unroll
      for (int fm = 0; fm < 4; ++fm)
#pragma unroll
        for (int fn = 0; fn < 4; ++fn)
          acc[fm][fn] = MFMA_BF16(af[fm], bfr[fn], acc[fm][fn]);
    }
    __syncthreads();
  }
}

// ---------- GEMM1: qkv = x @ Wqkv + b; scatter q(k scaled), k, vT per head ----------
__global__ __launch_bounds__(256, 2) void k_gemm_qkv(const bf16_t* __restrict__ xb,
                                                     const bf16_t* __restrict__ WqkvT,
                                                     const float* __restrict__ bqkv,
                                                     bf16_t* __restrict__ qb,
                                                     bf16_t* __restrict__ kb,
                                                     bf16_t* __restrict__ vtb) {
  __shared__ u16 As[128 * 80];
  __shared__ u16 Bs[128 * 80];
  f32x4_t acc[4][4];
  int bid = blockIdx.x;
  int tn = bid % 24, tm = bid / 24;
  int m0 = tm * 128, n0 = tn * 128;
  gemm_core_128(xb, WqkvT, m0, n0, As, Bs, acc);

  const int tid = threadIdx.x, w = tid >> 6, l = tid & 63, g = l >> 4, li = l & 15;
  const int wm = w >> 1, wn = w & 1;
  const int which = n0 >> 10;  // 0=q 1=k 2=v (tile never crosses boundary)
#pragma unroll
  for (int fm = 0; fm < 4; ++fm) {
#pragma unroll
    for (int fn = 0; fn < 4; ++fn) {
      int n = n0 + wn * 64 + fn * 16 + li;
      float bias = bqkv[n];
      int d = n & 1023, h = d >> 6, hd = d & 63;
      int mbase = m0 + wm * 64 + fm * 16 + g * 4;
      int b = mbase >> 11, s = mbase & 2047;  // s..s+3
      int bh = b * HH + h;
      if (which == 0) {
#pragma unroll
        for (int r = 0; r < 4; ++r) {
          float v = (acc[fm][fn][r] + bias) * 0.125f;  // 1/sqrt(64)
          qb[((long)bh * SS + s + r) * HDD + hd] = (bf16_t)v;
        }
      } else if (which == 1) {
#pragma unroll
        for (int r = 0; r < 4; ++r)
          kb[((long)bh * SS + s + r) * HDD + hd] = (bf16_t)(acc[fm][fn][r] + bias);
      } else {
        bf16x4_t pv;
#pragma unroll
        for (int r = 0; r < 4; ++r) pv[r] = (bf16_t)(acc[fm][fn][r] + bias);
        *reinterpret_cast<bf16x4_t*>(&vtb[((long)bh * HDD + hd) * SS + s]) = pv;
      }
    }
  }
}

// ---------- flash attention, causal; 64-row Q tile per block, 4 waves x 16 rows ----------
__global__ __launch_bounds__(256, 2) void k_attn(const bf16_t* __restrict__ qb,
                                                 const bf16_t* __restrict__ kb,
                                                 const bf16_t* __restrict__ vtb,
                                                 bf16_t* __restrict__ ctx) {
  __shared__ u16 Plds[4][16 * 80];
  int bid = blockIdx.x;
  int bh = bid >> 5, qt = bid & 31;
  int tid = threadIdx.x, w = tid >> 6, l = tid & 63, g = l >> 4, li = l & 15;
  int q0 = qt * 64;

  const bf16_t* qrow = qb + ((long)bh * SS + q0 + w * 16 + li) * HDD;
  bf16x8_t qa[2];
  qa[0] = load8(qrow + g * 8);
  qa[1] = load8(qrow + 32 + g * 8);

  const bf16_t* Kb = kb + (long)bh * SS * HDD;
  const bf16_t* Vb = vtb + (long)bh * HDD * SS;
  u16* Pw = &Plds[w][0];

  float mrow[4], lrow[4];
  f32x4_t acc[4];
#pragma unroll
  for (int r = 0; r < 4; ++r) { mrow[r] = -1e30f; lrow[r] = 0.f; }
#pragma unroll
  for (int fd = 0; fd < 4; ++fd) acc[fd] = zero4();

  for (int j = 0; j <= qt; ++j) {
    int k0 = j * 64;
    f32x4_t sf[4];
#pragma unroll
    for (int fc = 0; fc < 4; ++fc) {
      sf[fc] = zero4();
#pragma unroll
      for (int ds = 0; ds < 2; ++ds) {
        bf16x8_t kf = load8(Kb + (long)(k0 + fc * 16 + li) * HDD + ds * 32 + g * 8);
        sf[fc] = MFMA_BF16(qa[ds], kf, sf[fc]);
      }
    }
    if (j == qt) {  // diagonal tile: causal mask
#pragma unroll
      for (int fc = 0; fc < 4; ++fc)
#pragma unroll
        for (int r = 0; r < 4; ++r) {
          int col = fc * 16 + li, row = w * 16 + g * 4 + r;
          if (col > row) sf[fc][r] = -1e30f;
        }
    }
    // online softmax (rows live in 16-lane groups)
    float sc[4];
#pragma unroll
    for (int r = 0; r < 4; ++r) {
      float pm = fmaxf(fmaxf(sf[0][r], sf[1][r]), fmaxf(sf[2][r], sf[3][r]));
#pragma unroll
      for (int off = 8; off; off >>= 1) pm = fmaxf(pm, __shfl_xor(pm, off));
      float mnew = fmaxf(mrow[r], pm);
      sc[r] = __expf(mrow[r] - mnew);
      mrow[r] = mnew;
    }
    float rs[4];
#pragma unroll
    for (int r = 0; r < 4; ++r) rs[r] = 0.f;
#pragma unroll
    for (int fc = 0; fc < 4; ++fc)
#pragma unroll
      for (int r = 0; r < 4; ++r) {
        float p = __expf(sf[fc][r] - mrow[r]);
        sf[fc][r] = p;
        rs[r] += p;
      }
#pragma unroll
    for (int r = 0; r < 4; ++r) {
#pragma unroll
      for (int off = 8; off; off >>= 1) rs[r] += __shfl_xor(rs[r], off);
      lrow[r] = lrow[r] * sc[r] + rs[r];
    }
#pragma unroll
    for (int fd = 0; fd < 4; ++fd)
#pragma unroll
      for (int r = 0; r < 4; ++r) acc[fd][r] *= sc[r];
    // P stripe -> LDS (bf16), wave-private, pitch 80
#pragma unroll
    for (int fc = 0; fc < 4; ++fc)
#pragma unroll
      for (int r = 0; r < 4; ++r)
        Pw[(g * 4 + r) * 80 + fc * 16 + li] = __builtin_bit_cast(u16, (bf16_t)sf[fc][r]);
    // PV
#pragma unroll
    for (int ss = 0; ss < 2; ++ss) {
      bf16x8_t pa = load8(&Pw[li * 80 + ss * 32 + g * 8]);
#pragma unroll
      for (int fd = 0; fd < 4; ++fd) {
        bf16x8_t vf = load8(Vb + (long)(fd * 16 + li) * SS + k0 + ss * 32 + g * 8);
        acc[fd] = MFMA_BF16(pa, vf, acc[fd]);
      }
    }
  }
  // epilogue: ctx[b][s][h*64+d] bf16
  int b = bh >> 4, h = bh & 15;
#pragma unroll
  for (int fd = 0; fd < 4; ++fd)
#pragma unroll
    for (int r = 0; r < 4; ++r) {
      int srow = q0 + w * 16 + g * 4 + r;
      float v = acc[fd][r] / lrow[r];
      ctx[((long)b * SS + srow) * DD + h * HDD + fd * 16 + li] = (bf16_t)v;
    }
}

// ---------- GEMM3: out = ctx @ Wout + bout (f32 out) ----------
__global__ __launch_bounds__(256, 2) void k_gemm_out(const bf16_t* __restrict__ ctx,
                                                     const bf16_t* __restrict__ WoutT,
                                                     const float* __restrict__ bout,
                                                     float* __restrict__ out) {
  __shared__ u16 As[128 * 80];
  __shared__ u16 Bs[128 * 80];
  f32x4_t acc[4][4];
  int bid = blockIdx.x;
  int tn = bid & 7, tm = bid >> 3;
  int m0 = tm * 128, n0 = tn * 128;
  gemm_core_128(ctx, WoutT, m0, n0, As, Bs, acc);

  const int tid = threadIdx.x, w = tid >> 6, l = tid & 63, g = l >> 4, li = l & 15;
  const int wm = w >> 1, wn = w & 1;
#pragma unroll
  for (int fm = 0; fm < 4; ++fm)
#pragma unroll
    for (int fn = 0; fn < 4; ++fn) {
      int n = n0 + wn * 64 + fn * 16 + li;
      float bias = bout[n];
      int m = m0 + wm * 64 + fm * 16 + g * 4;
#pragma unroll
      for (int r = 0; r < 4; ++r)
        out[(long)(m + r) * DD + n] = acc[fm][fn][r] + bias;
    }
}

// ---------- launch ----------
extern "C" void kernel_launch(void* const* d_in, const int* in_sizes, int n_in,
                              void* d_out, int out_size, void* d_ws, size_t ws_size,
                              hipStream_t stream) {
  const float* x    = (const float*)d_in[0];
  // d_in[1] = causal mask (tril) — implemented analytically
  const float* Wqkv = (const float*)d_in[2];
  const float* bqkv = (const float*)d_in[3];
  const float* Wout = (const float*)d_in[4];
  const float* bout = (const float*)d_in[5];
  float* out = (float*)d_out;

  char* ws = (char*)d_ws;
  bf16_t* WqkvT = (bf16_t*)ws;                                   //  6 MB
  bf16_t* WoutT = (bf16_t*)(ws + 6291456);                       //  2 MB
  bf16_t* qb    = (bf16_t*)(ws + 6291456 + 2097152);             // 16 MB
  bf16_t* kb    = qb + (long)MR * DD;                            // 16 MB
  bf16_t* vtb   = kb + (long)MR * DD;                            // 16 MB
  bf16_t* xb    = vtb + (long)MR * DD;                           // 16 MB (reused as ctx)
  bf16_t* ctx   = xb;  // xb dead after gemm_qkv

  k_convert_x<<<MR * DD / 1024, 256, 0, stream>>>(x, xb);
  k_transpose<1024, 3072><<<(3072 / 64) * (1024 / 64), 256, 0, stream>>>(Wqkv, WqkvT);
  k_transpose<1024, 1024><<<(1024 / 64) * (1024 / 64), 256, 0, stream>>>(Wout, WoutT);
  k_gemm_qkv<<<(MR / 128) * (NQKV / 128), 256, 0, stream>>>(xb, WqkvT, bqkv, qb, kb, vtb);
  k_attn<<<BB * HH * (SS / 64), 256, 0, stream>>>(qb, kb, vtb, ctx);
  k_gemm_out<<<(MR / 128) * (DD / 128), 256, 0, stream>>>(ctx, WoutT, bout, out);
}

// Round 6
// 321.847 us; speedup vs baseline: 2.0090x; 2.0090x over previous
//
#include <hip/hip_runtime.h>

// ---------- types ----------
typedef __bf16 bf16_t;
typedef __bf16 bf16x4_t __attribute__((ext_vector_type(4)));
typedef __bf16 bf16x8_t __attribute__((ext_vector_type(8)));
typedef float  f32x4_t  __attribute__((ext_vector_type(4)));
typedef unsigned int u32x4_t __attribute__((ext_vector_type(4)));
typedef unsigned short u16;

#define MFMA_BF16(a, b, c) __builtin_amdgcn_mfma_f32_16x16x32_bf16((a), (b), (c), 0, 0, 0)

typedef __attribute__((address_space(1))) const unsigned int gu32_t;
typedef __attribute__((address_space(3))) unsigned int su32_t;
static __device__ __forceinline__ void gload_lds16(const void* g, void* l) {
  __builtin_amdgcn_global_load_lds((gu32_t*)g, (su32_t*)l, 16, 0, 0);
}

static __device__ __forceinline__ f32x4_t zero4() {
  f32x4_t z; z[0] = 0.f; z[1] = 0.f; z[2] = 0.f; z[3] = 0.f; return z;
}
static __device__ __forceinline__ bf16x8_t load8(const void* p) {
  return __builtin_bit_cast(bf16x8_t, *reinterpret_cast<const u32x4_t*>(p));
}

// ---------- problem constants ----------
constexpr int BB = 4, SS = 2048, DD = 1024, HH = 16, HDD = 64;
constexpr int MR = BB * SS;          // 8192 rows
constexpr int NQKV = 3 * DD;         // 3072

// ---------- x f32 -> bf16 ----------
__global__ __launch_bounds__(256, 2) void k_convert_x(const float* __restrict__ x,
                                                      bf16_t* __restrict__ xb) {
  int i = blockIdx.x * 256 + threadIdx.x;            // 4 elems each
  f32x4_t v = reinterpret_cast<const f32x4_t*>(x)[i];
  bf16x4_t o;
  o[0] = (bf16_t)v[0]; o[1] = (bf16_t)v[1]; o[2] = (bf16_t)v[2]; o[3] = (bf16_t)v[3];
  reinterpret_cast<bf16x4_t*>(xb)[i] = o;
}

// ---------- W [KD][ND] f32  ->  WT [ND][KD] bf16 ----------
template <int KD, int ND>
__global__ __launch_bounds__(256, 2) void k_transpose(const float* __restrict__ W,
                                                      bf16_t* __restrict__ WT) {
  __shared__ float tile[64][65];
  const int nt = ND / 64;
  int bx = blockIdx.x % nt;      // n tile
  int by = blockIdx.x / nt;      // k tile
  int k0 = by * 64, n0 = bx * 64;
  int t = threadIdx.x, cc = t & 63;
#pragma unroll
  for (int i = 0; i < 16; ++i) {
    int rr = (t >> 6) + i * 4;
    tile[rr][cc] = W[(k0 + rr) * ND + n0 + cc];
  }
  __syncthreads();
#pragma unroll
  for (int i = 0; i < 16; ++i) {
    int rr = (t >> 6) + i * 4;                       // n-row
    WT[(n0 + rr) * (long)KD + k0 + cc] = (bf16_t)tile[cc][rr];
  }
}

// ---------- shared 128x128 GEMM core, m97 structure ----------
// A [M][1024] bf16, BT [N][1024] bf16. Linear LDS [128][64], source-swizzled
// (chunk c stored at c^(row&7)) so ds_read_b128 is ~2-way conflict only.
__device__ __forceinline__ void gemm_core_128(const bf16_t* __restrict__ A,
                                              const bf16_t* __restrict__ BT,
                                              int m0, int n0,
                                              u16* As, u16* Bs, f32x4_t acc[4][4]) {
  const int tid = threadIdx.x;
  const int w = tid >> 6, l = tid & 63;
  const int g = l >> 4, li = l & 15;
  const int wm = w >> 1, wn = w & 1;
  const int srow = tid >> 3;                 // 0..31 (row within 32-row issue)
  const int sch = (tid & 7) ^ (srow & 7);    // pre-swizzled source chunk
#pragma unroll
  for (int i = 0; i < 4; ++i)
#pragma unroll
    for (int j = 0; j < 4; ++j) acc[i][j] = zero4();

  for (int kt = 0; kt < 16; ++kt) {
    const int k0 = kt * 64;
    const bf16_t* ga = A  + (long)(m0 + srow) * 1024 + k0 + sch * 8;
    const bf16_t* gb = BT + (long)(n0 + srow) * 1024 + k0 + sch * 8;
    char* la = (char*)As + w * 1024;
    char* lb = (char*)Bs + w * 1024;
#pragma unroll
    for (int i = 0; i < 4; ++i) {
      gload_lds16(ga + (long)i * 32 * 1024, la + i * 4096);
      gload_lds16(gb + (long)i * 32 * 1024, lb + i * 4096);
    }
    __syncthreads();   // drains vmcnt(0) -> staged data visible to all waves
#pragma unroll
    for (int kk = 0; kk < 2; ++kk) {
      const int c0 = ((kk * 4 + g) ^ (li & 7)) * 8;
      bf16x8_t af[4], bfr[4];
#pragma unroll
      for (int f = 0; f < 4; ++f) {
        af[f]  = load8(&As[(wm * 64 + f * 16 + li) * 64 + c0]);
        bfr[f] = load8(&Bs[(wn * 64 + f * 16 + li) * 64 + c0]);
      }
#pragma unroll
      for (int fm = 0; fm < 4; ++fm)
#pragma unroll
        for (int fn = 0; fn < 4; ++fn)
          acc[fm][fn] = MFMA_BF16(af[fm], bfr[fn], acc[fm][fn]);
    }
    __syncthreads();   // all waves done reading before next stage overwrites
  }
}

// ---------- GEMM1: qkv = x @ Wqkv + b; scatter q(scaled), k, vT per head ----------
__global__ __launch_bounds__(256, 2) void k_gemm_qkv(const bf16_t* __restrict__ xb,
                                                     const bf16_t* __restrict__ WqkvT,
                                                     const float* __restrict__ bqkv,
                                                     bf16_t* __restrict__ qb,
                                                     bf16_t* __restrict__ kb,
                                                     bf16_t* __restrict__ vtb) {
  __shared__ u16 As[128 * 64];
  __shared__ u16 Bs[128 * 64];
  f32x4_t acc[4][4];
  int nb = blockIdx.x;                       // 1536 wgs; XCD-contiguous remap
  int bid = (nb & 7) * 192 + (nb >> 3);
  int tn = bid % 24, tm = bid / 24;
  int m0 = tm * 128, n0 = tn * 128;
  gemm_core_128(xb, WqkvT, m0, n0, As, Bs, acc);

  const int tid = threadIdx.x, w = tid >> 6, l = tid & 63, g = l >> 4, li = l & 15;
  const int wm = w >> 1, wn = w & 1;
  const int which = n0 >> 10;  // 0=q 1=k 2=v (tile never crosses boundary)
#pragma unroll
  for (int fm = 0; fm < 4; ++fm) {
#pragma unroll
    for (int fn = 0; fn < 4; ++fn) {
      int n = n0 + wn * 64 + fn * 16 + li;
      float bias = bqkv[n];
      int d = n & 1023, h = d >> 6, hd = d & 63;
      int mbase = m0 + wm * 64 + fm * 16 + g * 4;
      int b = mbase >> 11, s = mbase & 2047;  // s..s+3
      int bh = b * HH + h;
      if (which == 0) {
#pragma unroll
        for (int r = 0; r < 4; ++r) {
          float v = (acc[fm][fn][r] + bias) * 0.125f;  // 1/sqrt(64)
          qb[((long)bh * SS + s + r) * HDD + hd] = (bf16_t)v;
        }
      } else if (which == 1) {
#pragma unroll
        for (int r = 0; r < 4; ++r)
          kb[((long)bh * SS + s + r) * HDD + hd] = (bf16_t)(acc[fm][fn][r] + bias);
      } else {
        bf16x4_t pv;
#pragma unroll
        for (int r = 0; r < 4; ++r) pv[r] = (bf16_t)(acc[fm][fn][r] + bias);
        *reinterpret_cast<bf16x4_t*>(&vtb[((long)bh * HDD + hd) * SS + s]) = pv;
      }
    }
  }
}

// ---------- flash attention, causal; 64-row Q tile/block, 4 waves x 16 rows ----------
// K/V tiles double-buffered in LDS via global_load_lds with pre-swizzled source
// (chunk c at physical c^(row&7)); reads apply the same XOR -> ~2-way conflicts.
__global__ __launch_bounds__(256, 4) void k_attn(const bf16_t* __restrict__ qb,
                                                 const bf16_t* __restrict__ kb,
                                                 const bf16_t* __restrict__ vtb,
                                                 bf16_t* __restrict__ ctx) {
  __shared__ u16 Ks[2][64 * 64];
  __shared__ u16 Vs[2][64 * 64];
  __shared__ u16 Plds[4][16 * 64];
  int nb = blockIdx.x;                       // 2048 wgs; XCD-contiguous remap
  int bid = (nb & 7) * 256 + (nb >> 3);
  int bh = bid >> 5, qt = bid & 31;
  int tid = threadIdx.x, w = tid >> 6, l = tid & 63, g = l >> 4, li = l & 15;
  int q0 = qt * 64;
  const int srow = tid >> 3;                 // 0..31
  const int sch = (tid & 7) ^ (srow & 7);    // pre-swizzled source chunk

  const bf16_t* qrow = qb + ((long)bh * SS + q0 + w * 16 + li) * HDD;
  bf16x8_t qa[2];
  qa[0] = load8(qrow + g * 8);
  qa[1] = load8(qrow + 32 + g * 8);

  const bf16_t* Kg = kb + (long)bh * SS * HDD;
  const bf16_t* Vg = vtb + (long)bh * HDD * SS;
  u16* Pw = &Plds[w][0];

  float mrow[4], lrow[4];
  f32x4_t acc[4];
#pragma unroll
  for (int r = 0; r < 4; ++r) { mrow[r] = -1e30f; lrow[r] = 0.f; }
#pragma unroll
  for (int fd = 0; fd < 4; ++fd) acc[fd] = zero4();

  // prologue: stage tile 0
  {
    char* lk = (char*)&Ks[0][0] + w * 1024;
    char* lv = (char*)&Vs[0][0] + w * 1024;
#pragma unroll
    for (int i = 0; i < 2; ++i) {
      gload_lds16(Kg + (long)(i * 32 + srow) * HDD + sch * 8, lk + i * 4096);
      gload_lds16(Vg + (long)(i * 32 + srow) * SS + sch * 8, lv + i * 4096);
    }
  }
  __syncthreads();

  int buf = 0;
  for (int j = 0; j <= qt; ++j) {
    if (j < qt) {  // prefetch next K/V tile into other buffer (overlaps compute)
      int k0n = (j + 1) * 64;
      char* lk = (char*)&Ks[buf ^ 1][0] + w * 1024;
      char* lv = (char*)&Vs[buf ^ 1][0] + w * 1024;
#pragma unroll
      for (int i = 0; i < 2; ++i) {
        gload_lds16(Kg + (long)(k0n + i * 32 + srow) * HDD + sch * 8, lk + i * 4096);
        gload_lds16(Vg + (long)(i * 32 + srow) * SS + k0n + sch * 8, lv + i * 4096);
      }
    }
    const u16* Ksb = &Ks[buf][0];
    const u16* Vsb = &Vs[buf][0];
    // QK^T
    f32x4_t sf[4];
    __builtin_amdgcn_s_setprio(1);
#pragma unroll
    for (int fc = 0; fc < 4; ++fc) {
      sf[fc] = zero4();
#pragma unroll
      for (int ds = 0; ds < 2; ++ds) {
        bf16x8_t kf = load8(&Ksb[(fc * 16 + li) * 64 + ((ds * 4 + g) ^ (li & 7)) * 8]);
        sf[fc] = MFMA_BF16(qa[ds], kf, sf[fc]);
      }
    }
    __builtin_amdgcn_s_setprio(0);
    if (j == qt) {  // diagonal tile: causal mask
#pragma unroll
      for (int fc = 0; fc < 4; ++fc)
#pragma unroll
        for (int r = 0; r < 4; ++r) {
          int col = fc * 16 + li, row = w * 16 + g * 4 + r;
          if (col > row) sf[fc][r] = -1e30f;
        }
    }
    // online softmax (each 16-lane group holds 4 q-rows)
    float sc[4];
#pragma unroll
    for (int r = 0; r < 4; ++r) {
      float pm = fmaxf(fmaxf(sf[0][r], sf[1][r]), fmaxf(sf[2][r], sf[3][r]));
#pragma unroll
      for (int off = 8; off; off >>= 1) pm = fmaxf(pm, __shfl_xor(pm, off));
      float mnew = fmaxf(mrow[r], pm);
      sc[r] = __expf(mrow[r] - mnew);
      mrow[r] = mnew;
    }
    float rs[4];
#pragma unroll
    for (int r = 0; r < 4; ++r) rs[r] = 0.f;
#pragma unroll
    for (int fc = 0; fc < 4; ++fc)
#pragma unroll
      for (int r = 0; r < 4; ++r) {
        float p = __expf(sf[fc][r] - mrow[r]);
        sf[fc][r] = p;
        rs[r] += p;
      }
#pragma unroll
    for (int r = 0; r < 4; ++r) {
#pragma unroll
      for (int off = 8; off; off >>= 1) rs[r] += __shfl_xor(rs[r], off);
      lrow[r] = lrow[r] * sc[r] + rs[r];
    }
#pragma unroll
    for (int fd = 0; fd < 4; ++fd)
#pragma unroll
      for (int r = 0; r < 4; ++r) acc[fd][r] *= sc[r];
    // P stripe -> wave-private LDS, swizzled [16][64]
#pragma unroll
    for (int fc = 0; fc < 4; ++fc)
#pragma unroll
      for (int r = 0; r < 4; ++r) {
        int prow = g * 4 + r;
        int c = (fc * 2 + (li >> 3)) ^ (prow & 7);
        Pw[prow * 64 + c * 8 + (li & 7)] = __builtin_bit_cast(u16, (bf16_t)sf[fc][r]);
      }
    // PV
    __builtin_amdgcn_s_setprio(1);
#pragma unroll
    for (int ss = 0; ss < 2; ++ss) {
      bf16x8_t pa = load8(&Pw[li * 64 + (((ss * 4 + g) ^ (li & 7)) * 8)]);
#pragma unroll
      for (int fd = 0; fd < 4; ++fd) {
        bf16x8_t vf = load8(&Vsb[(fd * 16 + li) * 64 + ((ss * 4 + g) ^ (li & 7)) * 8]);
        acc[fd] = MFMA_BF16(pa, vf, acc[fd]);
      }
    }
    __builtin_amdgcn_s_setprio(0);
    __syncthreads();   // next tile staged (vmcnt drained) + buf free for overwrite
    buf ^= 1;
  }
  // epilogue: ctx[b][s][h*64+d] bf16
  int b = bh >> 4, h = bh & 15;
#pragma unroll
  for (int fd = 0; fd < 4; ++fd)
#pragma unroll
    for (int r = 0; r < 4; ++r) {
      int srw = q0 + w * 16 + g * 4 + r;
      float v = acc[fd][r] / lrow[r];
      ctx[((long)b * SS + srw) * DD + h * HDD + fd * 16 + li] = (bf16_t)v;
    }
}

// ---------- GEMM3: out = ctx @ Wout + bout (f32 out) ----------
__global__ __launch_bounds__(256, 2) void k_gemm_out(const bf16_t* __restrict__ ctx,
                                                     const bf16_t* __restrict__ WoutT,
                                                     const float* __restrict__ bout,
                                                     float* __restrict__ out) {
  __shared__ u16 As[128 * 64];
  __shared__ u16 Bs[128 * 64];
  f32x4_t acc[4][4];
  int nb = blockIdx.x;                       // 512 wgs; XCD-contiguous remap
  int bid = (nb & 7) * 64 + (nb >> 3);
  int tn = bid & 7, tm = bid >> 3;
  int m0 = tm * 128, n0 = tn * 128;
  gemm_core_128(ctx, WoutT, m0, n0, As, Bs, acc);

  const int tid = threadIdx.x, w = tid >> 6, l = tid & 63, g = l >> 4, li = l & 15;
  const int wm = w >> 1, wn = w & 1;
#pragma unroll
  for (int fm = 0; fm < 4; ++fm)
#pragma unroll
    for (int fn = 0; fn < 4; ++fn) {
      int n = n0 + wn * 64 + fn * 16 + li;
      float bias = bout[n];
      int m = m0 + wm * 64 + fm * 16 + g * 4;
#pragma unroll
      for (int r = 0; r < 4; ++r)
        out[(long)(m + r) * DD + n] = acc[fm][fn][r] + bias;
    }
}

// ---------- launch ----------
extern "C" void kernel_launch(void* const* d_in, const int* in_sizes, int n_in,
                              void* d_out, int out_size, void* d_ws, size_t ws_size,
                              hipStream_t stream) {
  const float* x    = (const float*)d_in[0];
  // d_in[1] = causal mask (tril) — implemented analytically
  const float* Wqkv = (const float*)d_in[2];
  const float* bqkv = (const float*)d_in[3];
  const float* Wout = (const float*)d_in[4];
  const float* bout = (const float*)d_in[5];
  float* out = (float*)d_out;

  char* ws = (char*)d_ws;
  bf16_t* WqkvT = (bf16_t*)ws;                                   //  6 MB
  bf16_t* WoutT = (bf16_t*)(ws + 6291456);                       //  2 MB
  bf16_t* qb    = (bf16_t*)(ws + 6291456 + 2097152);             // 16 MB
  bf16_t* kb    = qb + (long)MR * DD;                            // 16 MB
  bf16_t* vtb   = kb + (long)MR * DD;                            // 16 MB
  bf16_t* xb    = vtb + (long)MR * DD;                           // 16 MB (reused as ctx)
  bf16_t* ctx   = xb;  // xb dead after gemm_qkv

  k_convert_x<<<MR * DD / 1024, 256, 0, stream>>>(x, xb);
  k_transpose<1024, 3072><<<(3072 / 64) * (1024 / 64), 256, 0, stream>>>(Wqkv, WqkvT);
  k_transpose<1024, 1024><<<(1024 / 64) * (1024 / 64), 256, 0, stream>>>(Wout, WoutT);
  k_gemm_qkv<<<(MR / 128) * (NQKV / 128), 256, 0, stream>>>(xb, WqkvT, bqkv, qb, kb, vtb);
  k_attn<<<BB * HH * (SS / 64), 256, 0, stream>>>(qb, kb, vtb, ctx);
  k_gemm_out<<<(MR / 128) * (DD / 128), 256, 0, stream>>>(ctx, WoutT, bout, out);
}

// Round 9
// 301.485 us; speedup vs baseline: 2.1447x; 1.0675x over previous
//
#include <hip/hip_runtime.h>

// ---------- types ----------
typedef __bf16 bf16_t;
typedef __bf16 bf16x4_t __attribute__((ext_vector_type(4)));
typedef __bf16 bf16x8_t __attribute__((ext_vector_type(8)));
typedef float  f32x4_t  __attribute__((ext_vector_type(4)));
typedef unsigned int u32x4_t __attribute__((ext_vector_type(4)));
typedef unsigned short u16;

#define MFMA_BF16(a, b, c) __builtin_amdgcn_mfma_f32_16x16x32_bf16((a), (b), (c), 0, 0, 0)

typedef __attribute__((address_space(1))) const unsigned int gu32_t;
typedef __attribute__((address_space(3))) unsigned int su32_t;
static __device__ __forceinline__ void gload_lds16(const void* g, void* l) {
  __builtin_amdgcn_global_load_lds((gu32_t*)g, (su32_t*)l, 16, 0, 0);
}

static __device__ __forceinline__ f32x4_t zero4() {
  f32x4_t z; z[0] = 0.f; z[1] = 0.f; z[2] = 0.f; z[3] = 0.f; return z;
}
static __device__ __forceinline__ bf16x8_t load8(const void* p) {
  return __builtin_bit_cast(bf16x8_t, *reinterpret_cast<const u32x4_t*>(p));
}

// ---------- problem constants ----------
constexpr int BB = 4, SS = 2048, DD = 1024, HH = 16, HDD = 64;
constexpr int MR = BB * SS;          // 8192 rows
constexpr int NQKV = 3 * DD;         // 3072

// ---------- x f32 -> bf16 ----------
__global__ __launch_bounds__(256, 2) void k_convert_x(const float* __restrict__ x,
                                                      bf16_t* __restrict__ xb) {
  int i = blockIdx.x * 256 + threadIdx.x;            // 4 elems each
  f32x4_t v = reinterpret_cast<const f32x4_t*>(x)[i];
  bf16x4_t o;
  o[0] = (bf16_t)v[0]; o[1] = (bf16_t)v[1]; o[2] = (bf16_t)v[2]; o[3] = (bf16_t)v[3];
  reinterpret_cast<bf16x4_t*>(xb)[i] = o;
}

// ---------- W [KD][ND] f32  ->  WT [ND][KD] bf16 ----------
template <int KD, int ND>
__global__ __launch_bounds__(256, 2) void k_transpose(const float* __restrict__ W,
                                                      bf16_t* __restrict__ WT) {
  __shared__ float tile[64][65];
  const int nt = ND / 64;
  int bx = blockIdx.x % nt;      // n tile
  int by = blockIdx.x / nt;      // k tile
  int k0 = by * 64, n0 = bx * 64;
  int t = threadIdx.x, cc = t & 63;
#pragma unroll
  for (int i = 0; i < 16; ++i) {
    int rr = (t >> 6) + i * 4;
    tile[rr][cc] = W[(k0 + rr) * ND + n0 + cc];
  }
  __syncthreads();
#pragma unroll
  for (int i = 0; i < 16; ++i) {
    int rr = (t >> 6) + i * 4;                       // n-row
    WT[(n0 + rr) * (long)KD + k0 + cc] = (bf16_t)tile[cc][rr];
  }
}

// ---------- shared 128x128 GEMM core, m97 structure ----------
// A [M][1024] bf16, BT [N][1024] bf16. Linear LDS [128][64], source-swizzled
// (chunk c stored at c^(row&7)) so ds_read_b128 is ~2-way conflict only.
__device__ __forceinline__ void gemm_core_128(const bf16_t* __restrict__ A,
                                              const bf16_t* __restrict__ BT,
                                              int m0, int n0,
                                              u16* As, u16* Bs, f32x4_t acc[4][4]) {
  const int tid = threadIdx.x;
  const int w = tid >> 6, l = tid & 63;
  const int g = l >> 4, li = l & 15;
  const int wm = w >> 1, wn = w & 1;
  const int srow = tid >> 3;                 // 0..31 (row within 32-row issue)
  const int sch = (tid & 7) ^ (srow & 7);    // pre-swizzled source chunk
#pragma unroll
  for (int i = 0; i < 4; ++i)
#pragma unroll
    for (int j = 0; j < 4; ++j) acc[i][j] = zero4();

  for (int kt = 0; kt < 16; ++kt) {
    const int k0 = kt * 64;
    const bf16_t* ga = A  + (long)(m0 + srow) * 1024 + k0 + sch * 8;
    const bf16_t* gb = BT + (long)(n0 + srow) * 1024 + k0 + sch * 8;
    char* la = (char*)As + w * 1024;
    char* lb = (char*)Bs + w * 1024;
#pragma unroll
    for (int i = 0; i < 4; ++i) {
      gload_lds16(ga + (long)i * 32 * 1024, la + i * 4096);
      gload_lds16(gb + (long)i * 32 * 1024, lb + i * 4096);
    }
    __syncthreads();   // drains vmcnt(0) -> staged data visible to all waves
#pragma unroll
    for (int kk = 0; kk < 2; ++kk) {
      const int c0 = ((kk * 4 + g) ^ (li & 7)) * 8;
      bf16x8_t af[4], bfr[4];
#pragma unroll
      for (int f = 0; f < 4; ++f) {
        af[f]  = load8(&As[(wm * 64 + f * 16 + li) * 64 + c0]);
        bfr[f] = load8(&Bs[(wn * 64 + f * 16 + li) * 64 + c0]);
      }
#pragma unroll
      for (int fm = 0; fm < 4; ++fm)
#pragma unroll
        for (int fn = 0; fn < 4; ++fn)
          acc[fm][fn] = MFMA_BF16(af[fm], bfr[fn], acc[fm][fn]);
    }
    __syncthreads();   // all waves done reading before next stage overwrites
  }
}

// ---------- GEMM1: qkv = x @ Wqkv + b; scatter q(scaled), k, vT per head ----------
__global__ __launch_bounds__(256, 2) void k_gemm_qkv(const bf16_t* __restrict__ xb,
                                                     const bf16_t* __restrict__ WqkvT,
                                                     const float* __restrict__ bqkv,
                                                     bf16_t* __restrict__ qb,
                                                     bf16_t* __restrict__ kb,
                                                     bf16_t* __restrict__ vtb) {
  __shared__ u16 As[128 * 64];
  __shared__ u16 Bs[128 * 64];
  f32x4_t acc[4][4];
  int nb = blockIdx.x;                       // 1536 wgs; XCD-contiguous remap
  int bid = (nb & 7) * 192 + (nb >> 3);
  int tn = bid % 24, tm = bid / 24;
  int m0 = tm * 128, n0 = tn * 128;
  gemm_core_128(xb, WqkvT, m0, n0, As, Bs, acc);

  const int tid = threadIdx.x, w = tid >> 6, l = tid & 63, g = l >> 4, li = l & 15;
  const int wm = w >> 1, wn = w & 1;
  const int which = n0 >> 10;  // 0=q 1=k 2=v (tile never crosses boundary)
#pragma unroll
  for (int fm = 0; fm < 4; ++fm) {
#pragma unroll
    for (int fn = 0; fn < 4; ++fn) {
      int n = n0 + wn * 64 + fn * 16 + li;
      float bias = bqkv[n];
      int d = n & 1023, h = d >> 6, hd = d & 63;
      int mbase = m0 + wm * 64 + fm * 16 + g * 4;
      int b = mbase >> 11, s = mbase & 2047;  // s..s+3
      int bh = b * HH + h;
      if (which == 0) {
#pragma unroll
        for (int r = 0; r < 4; ++r) {
          float v = (acc[fm][fn][r] + bias) * 0.125f;  // 1/sqrt(64)
          qb[((long)bh * SS + s + r) * HDD + hd] = (bf16_t)v;
        }
      } else if (which == 1) {
#pragma unroll
        for (int r = 0; r < 4; ++r)
          kb[((long)bh * SS + s + r) * HDD + hd] = (bf16_t)(acc[fm][fn][r] + bias);
      } else {
        bf16x4_t pv;
#pragma unroll
        for (int r = 0; r < 4; ++r) pv[r] = (bf16_t)(acc[fm][fn][r] + bias);
        *reinterpret_cast<bf16x4_t*>(&vtb[((long)bh * HDD + hd) * SS + s]) = pv;
      }
    }
  }
}

// ---------- flash attention, causal; 64-row Q tile/block, 4 waves x 16 rows ----------
// Swapped QK^T: S^T = MFMA(K,Q) puts a full k-row per lane (q = lane&15) ->
// softmax reduce is reg-local + 2 cross-lane hops instead of 4-deep chains x8.
__global__ __launch_bounds__(256, 4) void k_attn(const bf16_t* __restrict__ qb,
                                                 const bf16_t* __restrict__ kb,
                                                 const bf16_t* __restrict__ vtb,
                                                 bf16_t* __restrict__ ctx) {
  __shared__ u16 Ks[2][64 * 64];
  __shared__ u16 Vs[2][64 * 64];
  __shared__ u16 Plds[4][16 * 64];
  int nb = blockIdx.x;                       // 2048 wgs; XCD-contiguous remap
  int bid = (nb & 7) * 256 + (nb >> 3);
  int bh = bid >> 5, qt = bid & 31;
  int tid = threadIdx.x, w = tid >> 6, l = tid & 63, g = l >> 4, li = l & 15;
  int q0 = qt * 64;
  const int srow = tid >> 3;                 // 0..31
  const int sch = (tid & 7) ^ (srow & 7);    // pre-swizzled source chunk

  const bf16_t* qrow = qb + ((long)bh * SS + q0 + w * 16 + li) * HDD;
  bf16x8_t qa[2];
  qa[0] = load8(qrow + g * 8);
  qa[1] = load8(qrow + 32 + g * 8);

  const bf16_t* Kg = kb + (long)bh * SS * HDD;
  const bf16_t* Vg = vtb + (long)bh * HDD * SS;
  u16* Pw = &Plds[w][0];

  float m_s = -1e30f, l_s = 0.f;             // per-lane state for q = w*16+li
  f32x4_t acc[4];
#pragma unroll
  for (int fd = 0; fd < 4; ++fd) acc[fd] = zero4();

  // prologue: stage tile 0
  {
    char* lk = (char*)&Ks[0][0] + w * 1024;
    char* lv = (char*)&Vs[0][0] + w * 1024;
#pragma unroll
    for (int i = 0; i < 2; ++i) {
      gload_lds16(Kg + (long)(i * 32 + srow) * HDD + sch * 8, lk + i * 4096);
      gload_lds16(Vg + (long)(i * 32 + srow) * SS + sch * 8, lv + i * 4096);
    }
  }
  __syncthreads();

  int buf = 0;
  for (int j = 0; j <= qt; ++j) {
    if (j < qt) {  // prefetch next K/V tile into other buffer (overlaps compute)
      int k0n = (j + 1) * 64;
      char* lk = (char*)&Ks[buf ^ 1][0] + w * 1024;
      char* lv = (char*)&Vs[buf ^ 1][0] + w * 1024;
#pragma unroll
      for (int i = 0; i < 2; ++i) {
        gload_lds16(Kg + (long)(k0n + i * 32 + srow) * HDD + sch * 8, lk + i * 4096);
        gload_lds16(Vg + (long)(i * 32 + srow) * SS + k0n + sch * 8, lv + i * 4096);
      }
    }
    const u16* Ksb = &Ks[buf][0];
    const u16* Vsb = &Vs[buf][0];
    // QK^T, swapped: sfT[fc] row = k (fc*16+g*4+r), col = q (w*16+li)
    f32x4_t sfT[4];
    __builtin_amdgcn_s_setprio(1);
#pragma unroll
    for (int fc = 0; fc < 4; ++fc) {
      sfT[fc] = zero4();
#pragma unroll
      for (int ds = 0; ds < 2; ++ds) {
        bf16x8_t kf = load8(&Ksb[(fc * 16 + li) * 64 + ((ds * 4 + g) ^ (li & 7)) * 8]);
        sfT[fc] = MFMA_BF16(kf, qa[ds], sfT[fc]);
      }
    }
    __builtin_amdgcn_s_setprio(0);
    if (j == qt) {  // diagonal tile: causal mask (k > q)
#pragma unroll
      for (int fc = 0; fc < 4; ++fc)
#pragma unroll
        for (int r = 0; r < 4; ++r) {
          int kk = fc * 16 + g * 4 + r, qq = w * 16 + li;
          if (kk > qq) sfT[fc][r] = -1e30f;
        }
    }
    // online softmax: all 16 k-values for this lane's q are reg-local
    float pm01 = fmaxf(fmaxf(sfT[0][0], sfT[0][1]), fmaxf(sfT[0][2], sfT[0][3]));
    float pm23 = fmaxf(fmaxf(sfT[1][0], sfT[1][1]), fmaxf(sfT[1][2], sfT[1][3]));
    float pm45 = fmaxf(fmaxf(sfT[2][0], sfT[2][1]), fmaxf(sfT[2][2], sfT[2][3]));
    float pm67 = fmaxf(fmaxf(sfT[3][0], sfT[3][1]), fmaxf(sfT[3][2], sfT[3][3]));
    float pm = fmaxf(fmaxf(pm01, pm23), fmaxf(pm45, pm67));
    pm = fmaxf(pm, __shfl_xor(pm, 16));
    pm = fmaxf(pm, __shfl_xor(pm, 32));
    bool noresc = __all(pm <= m_s);          // exact: scale would be 1
    float mnew = fmaxf(m_s, pm);
    float scale = __expf(m_s - mnew);
    m_s = mnew;
    float rs = 0.f;
#pragma unroll
    for (int fc = 0; fc < 4; ++fc)
#pragma unroll
      for (int r = 0; r < 4; ++r) {
        float p = __expf(sfT[fc][r] - mnew);
        sfT[fc][r] = p;
        rs += p;
      }
    rs += __shfl_xor(rs, 16);
    rs += __shfl_xor(rs, 32);
    l_s = l_s * scale + rs;
    if (!noresc) {
      float scb[4];
#pragma unroll
      for (int r = 0; r < 4; ++r) scb[r] = __shfl(scale, g * 4 + r);  // to acc-row space
#pragma unroll
      for (int fd = 0; fd < 4; ++fd)
#pragma unroll
        for (int r = 0; r < 4; ++r) acc[fd][r] *= scb[r];
    }
    // P^T -> wave-private LDS as P[q=li][k], chunk-XOR swizzled
#pragma unroll
    for (int fc = 0; fc < 4; ++fc)
#pragma unroll
      for (int r = 0; r < 4; ++r) {
        int kk = fc * 16 + g * 4 + r;
        Pw[li * 64 + (((kk >> 3) ^ (li & 7)) * 8) + (kk & 7)] =
            __builtin_bit_cast(u16, (bf16_t)sfT[fc][r]);
      }
    // PV
    __builtin_amdgcn_s_setprio(1);
#pragma unroll
    for (int ss = 0; ss < 2; ++ss) {
      bf16x8_t pa = load8(&Pw[li * 64 + (((ss * 4 + g) ^ (li & 7)) * 8)]);
#pragma unroll
      for (int fd = 0; fd < 4; ++fd) {
        bf16x8_t vf = load8(&Vsb[(fd * 16 + li) * 64 + ((ss * 4 + g) ^ (li & 7)) * 8]);
        acc[fd] = MFMA_BF16(pa, vf, acc[fd]);
      }
    }
    __builtin_amdgcn_s_setprio(0);
    __syncthreads();   // next tile staged (vmcnt drained) + buf free for overwrite
    buf ^= 1;
  }
  // epilogue: ctx[b][s][h*64+d] bf16; l for acc-row q comes from lane g*4+r
  float lb[4];
#pragma unroll
  for (int r = 0; r < 4; ++r) lb[r] = __shfl(l_s, g * 4 + r);
  int b = bh >> 4, h = bh & 15;
#pragma unroll
  for (int fd = 0; fd < 4; ++fd)
#pragma unroll
    for (int r = 0; r < 4; ++r) {
      int srw = q0 + w * 16 + g * 4 + r;
      float v = acc[fd][r] / lb[r];
      ctx[((long)b * SS + srw) * DD + h * HDD + fd * 16 + li] = (bf16_t)v;
    }
}

// ---------- GEMM3: out = ctx @ Wout + bout (f32 out) ----------
__global__ __launch_bounds__(256, 2) void k_gemm_out(const bf16_t* __restrict__ ctx,
                                                     const bf16_t* __restrict__ WoutT,
                                                     const float* __restrict__ bout,
                                                     float* __restrict__ out) {
  __shared__ u16 As[128 * 64];
  __shared__ u16 Bs[128 * 64];
  f32x4_t acc[4][4];
  int nb = blockIdx.x;                       // 512 wgs; XCD-contiguous remap
  int bid = (nb & 7) * 64 + (nb >> 3);
  int tn = bid & 7, tm = bid >> 3;
  int m0 = tm * 128, n0 = tn * 128;
  gemm_core_128(ctx, WoutT, m0, n0, As, Bs, acc);

  const int tid = threadIdx.x, w = tid >> 6, l = tid & 63, g = l >> 4, li = l & 15;
  const int wm = w >> 1, wn = w & 1;
#pragma unroll
  for (int fm = 0; fm < 4; ++fm)
#pragma unroll
    for (int fn = 0; fn < 4; ++fn) {
      int n = n0 + wn * 64 + fn * 16 + li;
      float bias = bout[n];
      int m = m0 + wm * 64 + fm * 16 + g * 4;
#pragma unroll
      for (int r = 0; r < 4; ++r)
        out[(long)(m + r) * DD + n] = acc[fm][fn][r] + bias;
    }
}

// ---------- launch ----------
extern "C" void kernel_launch(void* const* d_in, const int* in_sizes, int n_in,
                              void* d_out, int out_size, void* d_ws, size_t ws_size,
                              hipStream_t stream) {
  const float* x    = (const float*)d_in[0];
  // d_in[1] = causal mask (tril) — implemented analytically
  const float* Wqkv = (const float*)d_in[2];
  const float* bqkv = (const float*)d_in[3];
  const float* Wout = (const float*)d_in[4];
  const float* bout = (const float*)d_in[5];
  float* out = (float*)d_out;

  char* ws = (char*)d_ws;
  bf16_t* WqkvT = (bf16_t*)ws;                                   //  6 MB
  bf16_t* WoutT = (bf16_t*)(ws + 6291456);                       //  2 MB
  bf16_t* qb    = (bf16_t*)(ws + 6291456 + 2097152);             // 16 MB
  bf16_t* kb    = qb + (long)MR * DD;                            // 16 MB
  bf16_t* vtb   = kb + (long)MR * DD;                            // 16 MB
  bf16_t* xb    = vtb + (long)MR * DD;                           // 16 MB (reused as ctx)
  bf16_t* ctx   = xb;  // xb dead after gemm_qkv

  k_convert_x<<<MR * DD / 1024, 256, 0, stream>>>(x, xb);
  k_transpose<1024, 3072><<<(3072 / 64) * (1024 / 64), 256, 0, stream>>>(Wqkv, WqkvT);
  k_transpose<1024, 1024><<<(1024 / 64) * (1024 / 64), 256, 0, stream>>>(Wout, WoutT);
  k_gemm_qkv<<<(MR / 128) * (NQKV / 128), 256, 0, stream>>>(xb, WqkvT, bqkv, qb, kb, vtb);
  k_attn<<<BB * HH * (SS / 64), 256, 0, stream>>>(qb, kb, vtb, ctx);
  k_gemm_out<<<(MR / 128) * (DD / 128), 256, 0, stream>>>(ctx, WoutT, bout, out);
}

// Round 10
// 281.553 us; speedup vs baseline: 2.2965x; 1.0708x over previous
//
#include <hip/hip_runtime.h>

// ---------- types ----------
typedef __bf16 bf16_t;
typedef __bf16 bf16x4_t __attribute__((ext_vector_type(4)));
typedef __bf16 bf16x8_t __attribute__((ext_vector_type(8)));
typedef float  f32x4_t  __attribute__((ext_vector_type(4)));
typedef unsigned int u32x4_t __attribute__((ext_vector_type(4)));
typedef unsigned short u16;

#define MFMA_BF16(a, b, c) __builtin_amdgcn_mfma_f32_16x16x32_bf16((a), (b), (c), 0, 0, 0)

typedef __attribute__((address_space(1))) const unsigned int gu32_t;
typedef __attribute__((address_space(3))) unsigned int su32_t;
static __device__ __forceinline__ void gload_lds16(const void* g, void* l) {
  __builtin_amdgcn_global_load_lds((gu32_t*)g, (su32_t*)l, 16, 0, 0);
}

static __device__ __forceinline__ f32x4_t zero4() {
  f32x4_t z; z[0] = 0.f; z[1] = 0.f; z[2] = 0.f; z[3] = 0.f; return z;
}
static __device__ __forceinline__ bf16x8_t load8(const void* p) {
  return __builtin_bit_cast(bf16x8_t, *reinterpret_cast<const u32x4_t*>(p));
}

// ---------- problem constants ----------
constexpr int BB = 4, SS = 2048, DD = 1024, HH = 16, HDD = 64;
constexpr int MR = BB * SS;          // 8192 rows
constexpr int NQKV = 3 * DD;         // 3072

// ---------- x f32 -> bf16 ----------
__global__ __launch_bounds__(256, 2) void k_convert_x(const float* __restrict__ x,
                                                      bf16_t* __restrict__ xb) {
  int i = blockIdx.x * 256 + threadIdx.x;            // 4 elems each
  f32x4_t v = reinterpret_cast<const f32x4_t*>(x)[i];
  bf16x4_t o;
  o[0] = (bf16_t)v[0]; o[1] = (bf16_t)v[1]; o[2] = (bf16_t)v[2]; o[3] = (bf16_t)v[3];
  reinterpret_cast<bf16x4_t*>(xb)[i] = o;
}

// ---------- W [KD][ND] f32  ->  WT [ND][KD] bf16 ----------
template <int KD, int ND>
__global__ __launch_bounds__(256, 2) void k_transpose(const float* __restrict__ W,
                                                      bf16_t* __restrict__ WT) {
  __shared__ float tile[64][65];
  const int nt = ND / 64;
  int bx = blockIdx.x % nt;      // n tile
  int by = blockIdx.x / nt;      // k tile
  int k0 = by * 64, n0 = bx * 64;
  int t = threadIdx.x, cc = t & 63;
#pragma unroll
  for (int i = 0; i < 16; ++i) {
    int rr = (t >> 6) + i * 4;
    tile[rr][cc] = W[(k0 + rr) * ND + n0 + cc];
  }
  __syncthreads();
#pragma unroll
  for (int i = 0; i < 16; ++i) {
    int rr = (t >> 6) + i * 4;                       // n-row
    WT[(n0 + rr) * (long)KD + k0 + cc] = (bf16_t)tile[cc][rr];
  }
}

// ---------- shared 128x128 GEMM core, m97 structure ----------
// A [M][1024] bf16, BT [N][1024] bf16. Linear LDS [128][64], source-swizzled
// (chunk c stored at c^(row&7)) so ds_read_b128 is ~2-way conflict only.
__device__ __forceinline__ void gemm_core_128(const bf16_t* __restrict__ A,
                                              const bf16_t* __restrict__ BT,
                                              int m0, int n0,
                                              u16* As, u16* Bs, f32x4_t acc[4][4]) {
  const int tid = threadIdx.x;
  const int w = tid >> 6, l = tid & 63;
  const int g = l >> 4, li = l & 15;
  const int wm = w >> 1, wn = w & 1;
  const int srow = tid >> 3;                 // 0..31 (row within 32-row issue)
  const int sch = (tid & 7) ^ (srow & 7);    // pre-swizzled source chunk
#pragma unroll
  for (int i = 0; i < 4; ++i)
#pragma unroll
    for (int j = 0; j < 4; ++j) acc[i][j] = zero4();

  for (int kt = 0; kt < 16; ++kt) {
    const int k0 = kt * 64;
    const bf16_t* ga = A  + (long)(m0 + srow) * 1024 + k0 + sch * 8;
    const bf16_t* gb = BT + (long)(n0 + srow) * 1024 + k0 + sch * 8;
    char* la = (char*)As + w * 1024;
    char* lb = (char*)Bs + w * 1024;
#pragma unroll
    for (int i = 0; i < 4; ++i) {
      gload_lds16(ga + (long)i * 32 * 1024, la + i * 4096);
      gload_lds16(gb + (long)i * 32 * 1024, lb + i * 4096);
    }
    __syncthreads();   // drains vmcnt(0) -> staged data visible to all waves
#pragma unroll
    for (int kk = 0; kk < 2; ++kk) {
      const int c0 = ((kk * 4 + g) ^ (li & 7)) * 8;
      bf16x8_t af[4], bfr[4];
#pragma unroll
      for (int f = 0; f < 4; ++f) {
        af[f]  = load8(&As[(wm * 64 + f * 16 + li) * 64 + c0]);
        bfr[f] = load8(&Bs[(wn * 64 + f * 16 + li) * 64 + c0]);
      }
#pragma unroll
      for (int fm = 0; fm < 4; ++fm)
#pragma unroll
        for (int fn = 0; fn < 4; ++fn)
          acc[fm][fn] = MFMA_BF16(af[fm], bfr[fn], acc[fm][fn]);
    }
    __syncthreads();   // all waves done reading before next stage overwrites
  }
}

// ---------- GEMM1: qkv = x @ Wqkv + b; scatter q(scaled), k, vT per head ----------
__global__ __launch_bounds__(256, 4) void k_gemm_qkv(const bf16_t* __restrict__ xb,
                                                     const bf16_t* __restrict__ WqkvT,
                                                     const float* __restrict__ bqkv,
                                                     bf16_t* __restrict__ qb,
                                                     bf16_t* __restrict__ kb,
                                                     bf16_t* __restrict__ vtb) {
  __shared__ u16 As[128 * 64];
  __shared__ u16 Bs[128 * 64];
  f32x4_t acc[4][4];
  int nb = blockIdx.x;                       // 1536 wgs; XCD-contiguous remap
  int bid = (nb & 7) * 192 + (nb >> 3);
  int tn = bid % 24, tm = bid / 24;
  int m0 = tm * 128, n0 = tn * 128;
  gemm_core_128(xb, WqkvT, m0, n0, As, Bs, acc);

  const int tid = threadIdx.x, w = tid >> 6, l = tid & 63, g = l >> 4, li = l & 15;
  const int wm = w >> 1, wn = w & 1;
  const int which = n0 >> 10;  // 0=q 1=k 2=v (tile never crosses boundary)
#pragma unroll
  for (int fm = 0; fm < 4; ++fm) {
#pragma unroll
    for (int fn = 0; fn < 4; ++fn) {
      int n = n0 + wn * 64 + fn * 16 + li;
      float bias = bqkv[n];
      int d = n & 1023, h = d >> 6, hd = d & 63;
      int mbase = m0 + wm * 64 + fm * 16 + g * 4;
      int b = mbase >> 11, s = mbase & 2047;  // s..s+3
      int bh = b * HH + h;
      if (which == 0) {
#pragma unroll
        for (int r = 0; r < 4; ++r) {
          float v = (acc[fm][fn][r] + bias) * 0.125f;  // 1/sqrt(64)
          qb[((long)bh * SS + s + r) * HDD + hd] = (bf16_t)v;
        }
      } else if (which == 1) {
#pragma unroll
        for (int r = 0; r < 4; ++r)
          kb[((long)bh * SS + s + r) * HDD + hd] = (bf16_t)(acc[fm][fn][r] + bias);
      } else {
        bf16x4_t pv;
#pragma unroll
        for (int r = 0; r < 4; ++r) pv[r] = (bf16_t)(acc[fm][fn][r] + bias);
        *reinterpret_cast<bf16x4_t*>(&vtb[((long)bh * HDD + hd) * SS + s]) = pv;
      }
    }
  }
}

// ---------- flash attention, causal; 64-row Q tile/block, 4 waves x 16 rows ----------
// Swapped QK^T (softmax reg-local) + heavy-first dispatch: qt=31 blocks launch
// first so the kernel tail drains on the cheap blocks (load-balance fix).
__global__ __launch_bounds__(256, 4) void k_attn(const bf16_t* __restrict__ qb,
                                                 const bf16_t* __restrict__ kb,
                                                 const bf16_t* __restrict__ vtb,
                                                 bf16_t* __restrict__ ctx) {
  __shared__ u16 Ks[2][64 * 64];
  __shared__ u16 Vs[2][64 * 64];
  __shared__ u16 Plds[4][16 * 64];
  int nb = blockIdx.x;                       // 2048 wgs
  int bh = nb & 63;                          // bh pinned to XCD (nb%8 stable)
  int qt = 31 - (nb >> 6);                   // heavy-first: qt descending
  int tid = threadIdx.x, w = tid >> 6, l = tid & 63, g = l >> 4, li = l & 15;
  int q0 = qt * 64;
  const int srow = tid >> 3;                 // 0..31
  const int sch = (tid & 7) ^ (srow & 7);    // pre-swizzled source chunk

  const bf16_t* qrow = qb + ((long)bh * SS + q0 + w * 16 + li) * HDD;
  bf16x8_t qa[2];
  qa[0] = load8(qrow + g * 8);
  qa[1] = load8(qrow + 32 + g * 8);

  const bf16_t* Kg = kb + (long)bh * SS * HDD;
  const bf16_t* Vg = vtb + (long)bh * HDD * SS;
  u16* Pw = &Plds[w][0];

  float m_s = -1e30f, l_s = 0.f;             // per-lane state for q = w*16+li
  f32x4_t acc[4];
#pragma unroll
  for (int fd = 0; fd < 4; ++fd) acc[fd] = zero4();

  // prologue: stage tile 0
  {
    char* lk = (char*)&Ks[0][0] + w * 1024;
    char* lv = (char*)&Vs[0][0] + w * 1024;
#pragma unroll
    for (int i = 0; i < 2; ++i) {
      gload_lds16(Kg + (long)(i * 32 + srow) * HDD + sch * 8, lk + i * 4096);
      gload_lds16(Vg + (long)(i * 32 + srow) * SS + sch * 8, lv + i * 4096);
    }
  }
  __syncthreads();

  int buf = 0;
  for (int j = 0; j <= qt; ++j) {
    if (j < qt) {  // prefetch next K/V tile into other buffer (overlaps compute)
      int k0n = (j + 1) * 64;
      char* lk = (char*)&Ks[buf ^ 1][0] + w * 1024;
      char* lv = (char*)&Vs[buf ^ 1][0] + w * 1024;
#pragma unroll
      for (int i = 0; i < 2; ++i) {
        gload_lds16(Kg + (long)(k0n + i * 32 + srow) * HDD + sch * 8, lk + i * 4096);
        gload_lds16(Vg + (long)(i * 32 + srow) * SS + k0n + sch * 8, lv + i * 4096);
      }
    }
    const u16* Ksb = &Ks[buf][0];
    const u16* Vsb = &Vs[buf][0];
    // QK^T, swapped: sfT[fc] row = k (fc*16+g*4+r), col = q (w*16+li)
    f32x4_t sfT[4];
    __builtin_amdgcn_s_setprio(1);
#pragma unroll
    for (int fc = 0; fc < 4; ++fc) {
      sfT[fc] = zero4();
#pragma unroll
      for (int ds = 0; ds < 2; ++ds) {
        bf16x8_t kf = load8(&Ksb[(fc * 16 + li) * 64 + ((ds * 4 + g) ^ (li & 7)) * 8]);
        sfT[fc] = MFMA_BF16(kf, qa[ds], sfT[fc]);
      }
    }
    __builtin_amdgcn_s_setprio(0);
    if (j == qt) {  // diagonal tile: causal mask (k > q)
#pragma unroll
      for (int fc = 0; fc < 4; ++fc)
#pragma unroll
        for (int r = 0; r < 4; ++r) {
          int kk = fc * 16 + g * 4 + r, qq = w * 16 + li;
          if (kk > qq) sfT[fc][r] = -1e30f;
        }
    }
    // online softmax: all 16 k-values for this lane's q are reg-local
    float pm01 = fmaxf(fmaxf(sfT[0][0], sfT[0][1]), fmaxf(sfT[0][2], sfT[0][3]));
    float pm23 = fmaxf(fmaxf(sfT[1][0], sfT[1][1]), fmaxf(sfT[1][2], sfT[1][3]));
    float pm45 = fmaxf(fmaxf(sfT[2][0], sfT[2][1]), fmaxf(sfT[2][2], sfT[2][3]));
    float pm67 = fmaxf(fmaxf(sfT[3][0], sfT[3][1]), fmaxf(sfT[3][2], sfT[3][3]));
    float pm = fmaxf(fmaxf(pm01, pm23), fmaxf(pm45, pm67));
    pm = fmaxf(pm, __shfl_xor(pm, 16));
    pm = fmaxf(pm, __shfl_xor(pm, 32));
    bool noresc = __all(pm <= m_s);          // exact: scale would be 1
    float mnew = fmaxf(m_s, pm);
    float scale = __expf(m_s - mnew);
    m_s = mnew;
    float rs = 0.f;
#pragma unroll
    for (int fc = 0; fc < 4; ++fc)
#pragma unroll
      for (int r = 0; r < 4; ++r) {
        float p = __expf(sfT[fc][r] - mnew);
        sfT[fc][r] = p;
        rs += p;
      }
    rs += __shfl_xor(rs, 16);
    rs += __shfl_xor(rs, 32);
    l_s = l_s * scale + rs;
    if (!noresc) {
      float scb[4];
#pragma unroll
      for (int r = 0; r < 4; ++r) scb[r] = __shfl(scale, g * 4 + r);  // to acc-row space
#pragma unroll
      for (int fd = 0; fd < 4; ++fd)
#pragma unroll
        for (int r = 0; r < 4; ++r) acc[fd][r] *= scb[r];
    }
    // P^T -> wave-private LDS as P[q=li][k], chunk-XOR swizzled
#pragma unroll
    for (int fc = 0; fc < 4; ++fc)
#pragma unroll
      for (int r = 0; r < 4; ++r) {
        int kk = fc * 16 + g * 4 + r;
        Pw[li * 64 + (((kk >> 3) ^ (li & 7)) * 8) + (kk & 7)] =
            __builtin_bit_cast(u16, (bf16_t)sfT[fc][r]);
      }
    // PV
    __builtin_amdgcn_s_setprio(1);
#pragma unroll
    for (int ss = 0; ss < 2; ++ss) {
      bf16x8_t pa = load8(&Pw[li * 64 + (((ss * 4 + g) ^ (li & 7)) * 8)]);
#pragma unroll
      for (int fd = 0; fd < 4; ++fd) {
        bf16x8_t vf = load8(&Vsb[(fd * 16 + li) * 64 + ((ss * 4 + g) ^ (li & 7)) * 8]);
        acc[fd] = MFMA_BF16(pa, vf, acc[fd]);
      }
    }
    __builtin_amdgcn_s_setprio(0);
    __syncthreads();   // next tile staged (vmcnt drained) + buf free for overwrite
    buf ^= 1;
  }
  // epilogue: ctx[b][s][h*64+d] bf16; l for acc-row q comes from lane g*4+r
  float lb[4];
#pragma unroll
  for (int r = 0; r < 4; ++r) lb[r] = __shfl(l_s, g * 4 + r);
  int b = bh >> 4, h = bh & 15;
#pragma unroll
  for (int fd = 0; fd < 4; ++fd)
#pragma unroll
    for (int r = 0; r < 4; ++r) {
      int srw = q0 + w * 16 + g * 4 + r;
      float v = acc[fd][r] / lb[r];
      ctx[((long)b * SS + srw) * DD + h * HDD + fd * 16 + li] = (bf16_t)v;
    }
}

// ---------- GEMM3: out = ctx @ Wout + bout (f32 out) ----------
__global__ __launch_bounds__(256, 4) void k_gemm_out(const bf16_t* __restrict__ ctx,
                                                     const bf16_t* __restrict__ WoutT,
                                                     const float* __restrict__ bout,
                                                     float* __restrict__ out) {
  __shared__ u16 As[128 * 64];
  __shared__ u16 Bs[128 * 64];
  f32x4_t acc[4][4];
  int nb = blockIdx.x;                       // 512 wgs; XCD-contiguous remap
  int bid = (nb & 7) * 64 + (nb >> 3);
  int tn = bid & 7, tm = bid >> 3;
  int m0 = tm * 128, n0 = tn * 128;
  gemm_core_128(ctx, WoutT, m0, n0, As, Bs, acc);

  const int tid = threadIdx.x, w = tid >> 6, l = tid & 63, g = l >> 4, li = l & 15;
  const int wm = w >> 1, wn = w & 1;
#pragma unroll
  for (int fm = 0; fm < 4; ++fm)
#pragma unroll
    for (int fn = 0; fn < 4; ++fn) {
      int n = n0 + wn * 64 + fn * 16 + li;
      float bias = bout[n];
      int m = m0 + wm * 64 + fm * 16 + g * 4;
#pragma unroll
      for (int r = 0; r < 4; ++r)
        out[(long)(m + r) * DD + n] = acc[fm][fn][r] + bias;
    }
}

// ---------- launch ----------
extern "C" void kernel_launch(void* const* d_in, const int* in_sizes, int n_in,
                              void* d_out, int out_size, void* d_ws, size_t ws_size,
                              hipStream_t stream) {
  const float* x    = (const float*)d_in[0];
  // d_in[1] = causal mask (tril) — implemented analytically
  const float* Wqkv = (const float*)d_in[2];
  const float* bqkv = (const float*)d_in[3];
  const float* Wout = (const float*)d_in[4];
  const float* bout = (const float*)d_in[5];
  float* out = (float*)d_out;

  char* ws = (char*)d_ws;
  bf16_t* WqkvT = (bf16_t*)ws;                                   //  6 MB
  bf16_t* WoutT = (bf16_t*)(ws + 6291456);                       //  2 MB
  bf16_t* qb    = (bf16_t*)(ws + 6291456 + 2097152);             // 16 MB
  bf16_t* kb    = qb + (long)MR * DD;                            // 16 MB
  bf16_t* vtb   = kb + (long)MR * DD;                            // 16 MB
  bf16_t* xb    = vtb + (long)MR * DD;                           // 16 MB (reused as ctx)
  bf16_t* ctx   = xb;  // xb dead after gemm_qkv

  k_convert_x<<<MR * DD / 1024, 256, 0, stream>>>(x, xb);
  k_transpose<1024, 3072><<<(3072 / 64) * (1024 / 64), 256, 0, stream>>>(Wqkv, WqkvT);
  k_transpose<1024, 1024><<<(1024 / 64) * (1024 / 64), 256, 0, stream>>>(Wout, WoutT);
  k_gemm_qkv<<<(MR / 128) * (NQKV / 128), 256, 0, stream>>>(xb, WqkvT, bqkv, qb, kb, vtb);
  k_attn<<<BB * HH * (SS / 64), 256, 0, stream>>>(qb, kb, vtb, ctx);
  k_gemm_out<<<(MR / 128) * (DD / 128), 256, 0, stream>>>(ctx, WoutT, bout, out);
}